// Round 1
// baseline (865.993 us; speedup 1.0000x reference)
//
#include <hip/hip_runtime.h>

#define B_SZ 64
#define IN_F 8192
#define OUT_F 8192
#define NNZ 262144
#define EPS 1e-7f

// Kernel 1: tT[f*64 + b] = clip(tanh(x[b*IN_F + f]))
// LDS tile transpose: block handles 64 f-columns x 64 batches.
__global__ __launch_bounds__(256) void tanh_transpose_kernel(
    const float* __restrict__ x, float* __restrict__ tT) {
  __shared__ float lds[64 * 65];
  const int f0 = blockIdx.x * 64;
  const int tid = threadIdx.x;
#pragma unroll
  for (int i = 0; i < 16; ++i) {
    int idx = tid + i * 256;
    int f = idx & 63;        // fast index -> coalesced global read
    int b = idx >> 6;
    float v = x[b * IN_F + f0 + f];
    v = tanhf(v);
    v = fminf(fmaxf(v, -1.0f + EPS), 1.0f - EPS);
    lds[f * 65 + b] = v;     // (f+b)%32 banks: 2-way, free
  }
  __syncthreads();
#pragma unroll
  for (int i = 0; i < 16; ++i) {
    int idx = tid + i * 256;
    int b = idx & 63;        // fast index -> coalesced global write
    int f = idx >> 6;
    tT[(f0 + f) * 64 + b] = lds[f * 65 + b];
  }
}

// Kernel 2: one wave per edge, lane = batch index.
// Chebyshev recurrence in registers; one fp32 atomic per lane.
__global__ __launch_bounds__(256) void edge_kernel(
    const float* __restrict__ tT, const float* __restrict__ w,
    const int* __restrict__ rows, const int* __restrict__ cols,
    float* __restrict__ y) {
  const int e = (blockIdx.x << 2) + (threadIdx.x >> 6);
  const int lane = threadIdx.x & 63;
  const int r = rows[e];   // wave-uniform broadcast loads
  const int c = cols[e];
  const float t = tT[(c << 6) + lane];         // coalesced 256B/wave
  const float4* wp = (const float4*)(w + ((size_t)e << 3));
  const float4 wa = wp[0];
  const float4 wb = wp[1];
  const float t2 = t + t;
  const float T1 = t;
  const float T2 = fmaf(t2, T1, -1.0f);
  const float T3 = fmaf(t2, T2, -T1);
  const float T4 = fmaf(t2, T3, -T2);
  const float T5 = fmaf(t2, T4, -T3);
  const float T6 = fmaf(t2, T5, -T4);
  const float T7 = fmaf(t2, T6, -T5);
  float acc = fmaf(wa.y, T1, wa.x);
  acc = fmaf(wa.z, T2, acc);
  acc = fmaf(wa.w, T3, acc);
  acc = fmaf(wb.x, T4, acc);
  acc = fmaf(wb.y, T5, acc);
  acc = fmaf(wb.z, T6, acc);
  acc = fmaf(wb.w, T7, acc);
  atomicAdd(&y[lane * OUT_F + r], acc);
}

extern "C" void kernel_launch(void* const* d_in, const int* in_sizes, int n_in,
                              void* d_out, int out_size, void* d_ws, size_t ws_size,
                              hipStream_t stream) {
  const float* x    = (const float*)d_in[0];
  const float* w    = (const float*)d_in[1];
  const int*   rows = (const int*)d_in[2];
  const int*   cols = (const int*)d_in[3];
  float* y  = (float*)d_out;
  float* tT = (float*)d_ws;   // IN_F * B_SZ floats = 2 MB

  // d_out is poisoned 0xAA before every call — zero it (async, capturable).
  hipMemsetAsync(d_out, 0, (size_t)out_size * sizeof(float), stream);

  tanh_transpose_kernel<<<IN_F / 64, 256, 0, stream>>>(x, tT);
  edge_kernel<<<NNZ / 4, 256, 0, stream>>>(tT, w, rows, cols, y);
}

// Round 2
// 135.109 us; speedup vs baseline: 6.4096x; 6.4096x over previous
//
#include <hip/hip_runtime.h>

#define B_SZ 64
#define IN_F 8192
#define OUT_F 8192
#define NNZ 262144
#define EPS 1e-7f

// ---------------- Workspace layout (d_ws) ----------------
// [0)        tT        : IN_F*64 floats   = 2 MB
// [2MB)      yT        : OUT_F*64 floats  = 2 MB
// [4MB)      cnt       : OUT_F ints       = 32 KB
// [4MB+64KB) off       : OUT_F+1 ints
// [4MB+128K) cur       : OUT_F ints
// [4MB+256K) sortedEid : NNZ ints         = 1 MB
// [5MB+256K) sortedCol : NNZ ints         = 1 MB
#define WS_TT   0
#define WS_YT   (2u << 20)
#define WS_CNT  (4u << 20)
#define WS_OFF  ((4u << 20) + (64u << 10))
#define WS_CUR  ((4u << 20) + (128u << 10))
#define WS_SEID ((4u << 20) + (256u << 10))
#define WS_SCOL ((5u << 20) + (256u << 10))

// Kernel 1: tT[f*64 + b] = clip(tanh(x[b*IN_F + f]))
__global__ __launch_bounds__(256) void tanh_transpose_kernel(
    const float* __restrict__ x, float* __restrict__ tT) {
  __shared__ float lds[64 * 65];
  const int f0 = blockIdx.x * 64;
  const int tid = threadIdx.x;
#pragma unroll
  for (int i = 0; i < 16; ++i) {
    int idx = tid + i * 256;
    int f = idx & 63;  // fast -> coalesced global read
    int b = idx >> 6;
    float v = x[b * IN_F + f0 + f];
    v = tanhf(v);
    v = fminf(fmaxf(v, -1.0f + EPS), 1.0f - EPS);
    lds[f * 65 + b] = v;
  }
  __syncthreads();
#pragma unroll
  for (int i = 0; i < 16; ++i) {
    int idx = tid + i * 256;
    int b = idx & 63;  // fast -> coalesced global write
    int f = idx >> 6;
    tT[(f0 + f) * 64 + b] = lds[f * 65 + b];
  }
}

// Kernel 2: histogram of edge rows.
__global__ __launch_bounds__(256) void hist_kernel(
    const int* __restrict__ rows, int* __restrict__ cnt) {
  int e = blockIdx.x * 256 + threadIdx.x;
  atomicAdd(&cnt[rows[e]], 1);
}

// Kernel 3: single-block exclusive scan of cnt[0..OUT_F) -> off, cur.
__global__ __launch_bounds__(256) void scan_kernel(
    const int* __restrict__ cnt, int* __restrict__ off, int* __restrict__ cur) {
  __shared__ int lds[256];
  const int tid = threadIdx.x;
  const int base = tid * 32;
  int local[32];
  int sum = 0;
#pragma unroll
  for (int i = 0; i < 32; ++i) {
    int v = cnt[base + i];
    local[i] = sum;  // exclusive within chunk
    sum += v;
  }
  lds[tid] = sum;
  __syncthreads();
  // Hillis-Steele inclusive scan over 256 partials
  for (int d = 1; d < 256; d <<= 1) {
    int v = (tid >= d) ? lds[tid - d] : 0;
    __syncthreads();
    lds[tid] += v;
    __syncthreads();
  }
  int prefix = (tid == 0) ? 0 : lds[tid - 1];
#pragma unroll
  for (int i = 0; i < 32; ++i) {
    int o = prefix + local[i];
    off[base + i] = o;
    cur[base + i] = o;
  }
  if (tid == 255) off[OUT_F] = prefix + sum;  // == NNZ
}

// Kernel 4: scatter edges into row-sorted order.
__global__ __launch_bounds__(256) void scatter_kernel(
    const int* __restrict__ rows, const int* __restrict__ cols,
    int* __restrict__ cur, int* __restrict__ sEid, int* __restrict__ sCol) {
  int e = blockIdx.x * 256 + threadIdx.x;
  int r = rows[e];
  int pos = atomicAdd(&cur[r], 1);
  sEid[pos] = e;
  sCol[pos] = cols[e];
}

// Kernel 5: one wave per output row; accumulate in registers, plain store.
__global__ __launch_bounds__(256) void gather_kernel(
    const float* __restrict__ tT, const float* __restrict__ w,
    const int* __restrict__ off, const int* __restrict__ sEid,
    const int* __restrict__ sCol, float* __restrict__ yT) {
  const int wid = (blockIdx.x * 256 + threadIdx.x) >> 6;  // = row
  const int lane = threadIdx.x & 63;
  const int start = off[wid];
  const int end = off[wid + 1];
  float acc = 0.0f;
  for (int s = start; s < end; s += 64) {
    const int n = min(64, end - s);
    int eidv = 0, colv = 0;
    if (s + lane < end) {
      eidv = sEid[s + lane];  // coalesced
      colv = sCol[s + lane];  // coalesced
    }
    for (int i = 0; i < n; ++i) {
      const int ei = __shfl(eidv, i);
      const int ci = __shfl(colv, i);
      const float4* wp = (const float4*)(w + ((size_t)ei << 3));
      const float4 wa = wp[0];  // wave-uniform 32B broadcast
      const float4 wb = wp[1];
      const float t = tT[(ci << 6) + lane];  // coalesced 256B
      const float t2 = t + t;
      const float T1 = t;
      const float T2 = fmaf(t2, T1, -1.0f);
      const float T3 = fmaf(t2, T2, -T1);
      const float T4 = fmaf(t2, T3, -T2);
      const float T5 = fmaf(t2, T4, -T3);
      const float T6 = fmaf(t2, T5, -T4);
      const float T7 = fmaf(t2, T6, -T5);
      float c0 = fmaf(wa.y, T1, wa.x);
      c0 = fmaf(wa.z, T2, c0);
      c0 = fmaf(wa.w, T3, c0);
      c0 = fmaf(wb.x, T4, c0);
      c0 = fmaf(wb.y, T5, c0);
      c0 = fmaf(wb.z, T6, c0);
      c0 = fmaf(wb.w, T7, c0);
      acc += c0;
    }
  }
  yT[(wid << 6) + lane] = acc;  // coalesced
}

// Kernel 6: y[b*OUT_F + r] = yT[r*64 + b]
__global__ __launch_bounds__(256) void transpose_out_kernel(
    const float* __restrict__ yT, float* __restrict__ y) {
  __shared__ float lds[64 * 65];
  const int r0 = blockIdx.x * 64;
  const int tid = threadIdx.x;
#pragma unroll
  for (int i = 0; i < 16; ++i) {
    int idx = tid + i * 256;
    int b = idx & 63;  // fast -> coalesced read of yT
    int rr = idx >> 6;
    lds[b * 65 + rr] = yT[(r0 + rr) * 64 + b];
  }
  __syncthreads();
#pragma unroll
  for (int i = 0; i < 16; ++i) {
    int idx = tid + i * 256;
    int rr = idx & 63;  // fast -> coalesced write of y
    int b = idx >> 6;
    y[b * OUT_F + r0 + rr] = lds[b * 65 + rr];
  }
}

extern "C" void kernel_launch(void* const* d_in, const int* in_sizes, int n_in,
                              void* d_out, int out_size, void* d_ws, size_t ws_size,
                              hipStream_t stream) {
  const float* x    = (const float*)d_in[0];
  const float* w    = (const float*)d_in[1];
  const int*   rows = (const int*)d_in[2];
  const int*   cols = (const int*)d_in[3];
  float* y = (float*)d_out;

  char* ws = (char*)d_ws;
  float* tT   = (float*)(ws + WS_TT);
  float* yT   = (float*)(ws + WS_YT);
  int*   cnt  = (int*)(ws + WS_CNT);
  int*   off  = (int*)(ws + WS_OFF);
  int*   cur  = (int*)(ws + WS_CUR);
  int*   sEid = (int*)(ws + WS_SEID);
  int*   sCol = (int*)(ws + WS_SCOL);

  hipMemsetAsync(cnt, 0, OUT_F * sizeof(int), stream);

  tanh_transpose_kernel<<<IN_F / 64, 256, 0, stream>>>(x, tT);
  hist_kernel<<<NNZ / 256, 256, 0, stream>>>(rows, cnt);
  scan_kernel<<<1, 256, 0, stream>>>(cnt, off, cur);
  scatter_kernel<<<NNZ / 256, 256, 0, stream>>>(rows, cols, cur, sEid, sCol);
  gather_kernel<<<OUT_F / 4, 256, 0, stream>>>(tT, w, off, sEid, sCol, yT);
  transpose_out_kernel<<<OUT_F / 64, 256, 0, stream>>>(yT, y);
}

// Round 3
// 121.995 us; speedup vs baseline: 7.0986x; 1.1075x over previous
//
#include <hip/hip_runtime.h>

#define B_SZ 64
#define IN_F 8192
#define OUT_F 8192
#define NNZ 262144
#define EPS 1e-7f

// ---------------- Workspace layout (d_ws) ----------------
// [0)        tT    : IN_F*64 floats   = 2 MB
// [2MB)      yT    : OUT_F*64 floats  = 2 MB
// [4MB)      cnt   : OUT_F ints       = 32 KB
// [4MB+64K)  off   : OUT_F+1 ints
// [4MB+128K) cur   : OUT_F ints
// [4MB+256K) sPair : NNZ int2         = 2 MB
#define WS_TT    0
#define WS_YT    (2u << 20)
#define WS_CNT   (4u << 20)
#define WS_OFF   ((4u << 20) + (64u << 10))
#define WS_CUR   ((4u << 20) + (128u << 10))
#define WS_SPAIR ((4u << 20) + (256u << 10))

// Kernel 1: tT[f*64 + b] = clip(tanh(x[b*IN_F + f]))
__global__ __launch_bounds__(256) void tanh_transpose_kernel(
    const float* __restrict__ x, float* __restrict__ tT) {
  __shared__ float lds[64 * 65];
  const int f0 = blockIdx.x * 64;
  const int tid = threadIdx.x;
#pragma unroll
  for (int i = 0; i < 16; ++i) {
    int idx = tid + i * 256;
    int f = idx & 63;  // fast -> coalesced global read
    int b = idx >> 6;
    float v = x[b * IN_F + f0 + f];
    v = tanhf(v);
    v = fminf(fmaxf(v, -1.0f + EPS), 1.0f - EPS);
    lds[f * 65 + b] = v;
  }
  __syncthreads();
#pragma unroll
  for (int i = 0; i < 16; ++i) {
    int idx = tid + i * 256;
    int b = idx & 63;  // fast -> coalesced global write
    int f = idx >> 6;
    tT[(f0 + f) * 64 + b] = lds[f * 65 + b];
  }
}

// Kernel 2: histogram of edge rows, 4 edges/thread via int4.
__global__ __launch_bounds__(256) void hist_kernel(
    const int* __restrict__ rows, int* __restrict__ cnt) {
  int i = blockIdx.x * 256 + threadIdx.x;
  int4 r = ((const int4*)rows)[i];
  atomicAdd(&cnt[r.x], 1);
  atomicAdd(&cnt[r.y], 1);
  atomicAdd(&cnt[r.z], 1);
  atomicAdd(&cnt[r.w], 1);
}

// Kernel 3: single-block exclusive scan of cnt[0..OUT_F) -> off, cur.
__global__ __launch_bounds__(256) void scan_kernel(
    const int* __restrict__ cnt, int* __restrict__ off, int* __restrict__ cur) {
  __shared__ int lds[256];
  const int tid = threadIdx.x;
  const int4* c4 = (const int4*)(cnt + tid * 32);
  int4 v[8];
#pragma unroll
  for (int i = 0; i < 8; ++i) v[i] = c4[i];
  int local[32];
  int sum = 0;
#pragma unroll
  for (int i = 0; i < 8; ++i) {
    local[4 * i + 0] = sum; sum += v[i].x;
    local[4 * i + 1] = sum; sum += v[i].y;
    local[4 * i + 2] = sum; sum += v[i].z;
    local[4 * i + 3] = sum; sum += v[i].w;
  }
  lds[tid] = sum;
  __syncthreads();
  for (int d = 1; d < 256; d <<= 1) {
    int t = (tid >= d) ? lds[tid - d] : 0;
    __syncthreads();
    lds[tid] += t;
    __syncthreads();
  }
  int prefix = (tid == 0) ? 0 : lds[tid - 1];
#pragma unroll
  for (int i = 0; i < 8; ++i) {
    int4 o;
    o.x = prefix + local[4 * i + 0];
    o.y = prefix + local[4 * i + 1];
    o.z = prefix + local[4 * i + 2];
    o.w = prefix + local[4 * i + 3];
    ((int4*)(off + tid * 32))[i] = o;
    ((int4*)(cur + tid * 32))[i] = o;
  }
  if (tid == 255) off[OUT_F] = prefix + sum;  // == NNZ
}

// Kernel 4: scatter edges into row-sorted (eid,col) pairs; one 8B store each.
__global__ __launch_bounds__(256) void scatter_kernel(
    const int* __restrict__ rows, const int* __restrict__ cols,
    int* __restrict__ cur, int2* __restrict__ sPair) {
  int i = blockIdx.x * 256 + threadIdx.x;
  int4 r = ((const int4*)rows)[i];
  int4 c = ((const int4*)cols)[i];
  int e = i * 4;
  int p0 = atomicAdd(&cur[r.x], 1); sPair[p0] = make_int2(e + 0, c.x);
  int p1 = atomicAdd(&cur[r.y], 1); sPair[p1] = make_int2(e + 1, c.y);
  int p2 = atomicAdd(&cur[r.z], 1); sPair[p2] = make_int2(e + 2, c.z);
  int p3 = atomicAdd(&cur[r.w], 1); sPair[p3] = make_int2(e + 3, c.w);
}

// Per-edge Chebyshev dot: 15 FMAs on t = tT[col][lane].
__device__ __forceinline__ float cheb_dot(const float* __restrict__ tT,
                                          const float* __restrict__ w,
                                          int ei, int ci, int lane) {
  const float4* wp = (const float4*)(w + ((size_t)(unsigned)ei << 3));
  const float4 wa = wp[0];  // wave-uniform 32B broadcast
  const float4 wb = wp[1];
  const float t = tT[((unsigned)ci << 6) + lane];  // coalesced 256B
  const float t2 = t + t;
  float Tm = t;
  float Tc = fmaf(t2, t, -1.0f);            // T2
  float acc = fmaf(wa.y, t, wa.x);
  acc = fmaf(wa.z, Tc, acc);
  float Tn = fmaf(t2, Tc, -Tm);             // T3
  acc = fmaf(wa.w, Tn, acc);
  Tm = Tc; Tc = Tn;
  Tn = fmaf(t2, Tc, -Tm);                   // T4
  acc = fmaf(wb.x, Tn, acc);
  Tm = Tc; Tc = Tn;
  Tn = fmaf(t2, Tc, -Tm);                   // T5
  acc = fmaf(wb.y, Tn, acc);
  Tm = Tc; Tc = Tn;
  Tn = fmaf(t2, Tc, -Tm);                   // T6
  acc = fmaf(wb.z, Tn, acc);
  Tm = Tc; Tc = Tn;
  Tn = fmaf(t2, Tc, -Tm);                   // T7
  acc = fmaf(wb.w, Tn, acc);
  return acc;
}

// Kernel 5: one wave per output row; readlane -> uniform edge ids,
// 4 independent chains per iteration for latency hiding.
__global__ __launch_bounds__(256) void gather_kernel(
    const float* __restrict__ tT, const float* __restrict__ w,
    const int* __restrict__ off, const int2* __restrict__ sPair,
    float* __restrict__ yT) {
  const int row = (blockIdx.x * 256 + threadIdx.x) >> 6;
  const int lane = threadIdx.x & 63;
  const int start = off[row];
  const int end = off[row + 1];
  float acc = 0.0f;
  for (int s = start; s < end; s += 64) {
    const int n = min(64, end - s);
    int2 pr = make_int2(0, 0);
    if (s + lane < end) pr = sPair[s + lane];  // coalesced 8B/lane
    int i = 0;
    for (; i + 4 <= n; i += 4) {
      int e0 = __builtin_amdgcn_readlane(pr.x, i);
      int c0 = __builtin_amdgcn_readlane(pr.y, i);
      int e1 = __builtin_amdgcn_readlane(pr.x, i + 1);
      int c1 = __builtin_amdgcn_readlane(pr.y, i + 1);
      int e2 = __builtin_amdgcn_readlane(pr.x, i + 2);
      int c2 = __builtin_amdgcn_readlane(pr.y, i + 2);
      int e3 = __builtin_amdgcn_readlane(pr.x, i + 3);
      int c3 = __builtin_amdgcn_readlane(pr.y, i + 3);
      float a0 = cheb_dot(tT, w, e0, c0, lane);
      float a1 = cheb_dot(tT, w, e1, c1, lane);
      float a2 = cheb_dot(tT, w, e2, c2, lane);
      float a3 = cheb_dot(tT, w, e3, c3, lane);
      acc += (a0 + a1) + (a2 + a3);
    }
    for (; i < n; ++i) {
      int e0 = __builtin_amdgcn_readlane(pr.x, i);
      int c0 = __builtin_amdgcn_readlane(pr.y, i);
      acc += cheb_dot(tT, w, e0, c0, lane);
    }
  }
  yT[(row << 6) + lane] = acc;  // coalesced
}

// Kernel 6: y[b*OUT_F + r] = yT[r*64 + b]
__global__ __launch_bounds__(256) void transpose_out_kernel(
    const float* __restrict__ yT, float* __restrict__ y) {
  __shared__ float lds[64 * 65];
  const int r0 = blockIdx.x * 64;
  const int tid = threadIdx.x;
#pragma unroll
  for (int i = 0; i < 16; ++i) {
    int idx = tid + i * 256;
    int b = idx & 63;  // fast -> coalesced read of yT
    int rr = idx >> 6;
    lds[b * 65 + rr] = yT[(r0 + rr) * 64 + b];
  }
  __syncthreads();
#pragma unroll
  for (int i = 0; i < 16; ++i) {
    int idx = tid + i * 256;
    int rr = idx & 63;  // fast -> coalesced write of y
    int b = idx >> 6;
    y[b * OUT_F + r0 + rr] = lds[b * 65 + rr];
  }
}

extern "C" void kernel_launch(void* const* d_in, const int* in_sizes, int n_in,
                              void* d_out, int out_size, void* d_ws, size_t ws_size,
                              hipStream_t stream) {
  const float* x    = (const float*)d_in[0];
  const float* w    = (const float*)d_in[1];
  const int*   rows = (const int*)d_in[2];
  const int*   cols = (const int*)d_in[3];
  float* y = (float*)d_out;

  char* ws = (char*)d_ws;
  float* tT    = (float*)(ws + WS_TT);
  float* yT    = (float*)(ws + WS_YT);
  int*   cnt   = (int*)(ws + WS_CNT);
  int*   off   = (int*)(ws + WS_OFF);
  int*   cur   = (int*)(ws + WS_CUR);
  int2*  sPair = (int2*)(ws + WS_SPAIR);

  hipMemsetAsync(cnt, 0, OUT_F * sizeof(int), stream);

  tanh_transpose_kernel<<<IN_F / 64, 256, 0, stream>>>(x, tT);
  hist_kernel<<<NNZ / 1024, 256, 0, stream>>>(rows, cnt);
  scan_kernel<<<1, 256, 0, stream>>>(cnt, off, cur);
  scatter_kernel<<<NNZ / 1024, 256, 0, stream>>>(rows, cols, cur, sPair);
  gather_kernel<<<OUT_F / 4, 256, 0, stream>>>(tT, w, off, sPair, yT);
  transpose_out_kernel<<<OUT_F / 64, 256, 0, stream>>>(yT, y);
}